// Round 1
// 1255.043 us; speedup vs baseline: 1.5856x; 1.5856x over previous
//
#include <hip/hip_runtime.h>
#include <stdint.h>

#define U_NUM   100000
#define NNODES  200000
#define DIM     64
#define OUTDIM  256
#define NNZ     6400000

// ---- bucket decomposition ----
#define BSHIFT  6
#define BNODES  64                      // nodes per bucket (200000/64 = 3125 exact)
#define NB      (NNODES >> BSHIFT)      // 3125 buckets
#define BCAP    4096                    // LDS capacity per bucket (mean 2048, sd ~45)
#define NBLK    256                     // partition blocks
#define EPB     (NNZ / NBLK)            // 25000 edges per partition block

// ---------- ws layout (new path) ----------
// [0, 800000)                  : uint32 rowend (NNODES)
// [800000, 800000+NNZ*8)       : int2 pairs {packed_src_dlow | src, f32bits(val)}
// [52000000, +NB*4)            : uint32 bcnt (bucket counts -> exclusive starts)
// [52012500, +NBLK*NB*4)       : uint32 partials (per-block per-bucket counts -> offsets)
#define WS_ROWEND    0
#define WS_PAIRS     800000
#define WS_BCNT      52000000
#define WS_PART      52012500
#define WS_NEEDED_NEW ((size_t)WS_PART + (size_t)NBLK * NB * 4)   // 55,212,500
#define WS_NEEDED_OLD (800000 + (size_t)NNZ * 8)                  // 52,000,000

// Copy ego (user||item) into cols 0..63. Layers 1..3 write cols 64..255 fully.
__global__ void init_out(const float* __restrict__ user_emb,
                         const float* __restrict__ item_emb,
                         float* __restrict__ out) {
    int t = blockIdx.x * blockDim.x + threadIdx.x;   // NNODES*16 threads
    if (t >= NNODES * 16) return;
    int n = t >> 4;
    int c = (t & 15) << 2;
    const float* s = (n < U_NUM) ? (user_emb + (size_t)n * DIM + c)
                                 : (item_emb + (size_t)(n - U_NUM) * DIM + c);
    *(float4*)(out + (size_t)n * OUTDIM + c) = *(const float4*)s;
}

// ===================== NEW PATH: deterministic radix partition =====================

// Per-block LDS histogram of dst buckets; write private counts to partials[blk][*].
__global__ __launch_bounds__(1024) void bucket_hist(const int* __restrict__ edst,
                                                    uint32_t* __restrict__ partials) {
    __shared__ uint32_t h[NB];
    for (int i = threadIdx.x; i < NB; i += 1024) h[i] = 0u;
    __syncthreads();
    int blk = blockIdx.x;
    int e0 = blk * EPB;
    for (int i = threadIdx.x; i < EPB; i += 1024)
        atomicAdd(&h[(uint32_t)edst[e0 + i] >> BSHIFT], 1u);
    __syncthreads();
    for (int i = threadIdx.x; i < NB; i += 1024)
        partials[(size_t)blk * NB + i] = h[i];
}

// bcnt[b] = sum over blocks of partials[blk][b]   (coalesced: consecutive threads -> consecutive b)
__global__ void bucket_colsum(const uint32_t* __restrict__ partials,
                              uint32_t* __restrict__ bcnt) {
    int b = blockIdx.x * blockDim.x + threadIdx.x;
    if (b >= NB) return;
    uint32_t s = 0u;
    for (int blk = 0; blk < NBLK; ++blk) s += partials[(size_t)blk * NB + b];
    bcnt[b] = s;
}

// Single-workgroup exclusive scan over NB counters, in place.
__global__ __launch_bounds__(1024) void scan_bcnt(uint32_t* __restrict__ cnt) {
    __shared__ uint32_t lds[1024];
    __shared__ uint32_t s_carry;
    int t = threadIdx.x;
    if (t == 0) s_carry = 0u;
    __syncthreads();
    for (int base = 0; base < NB; base += 1024) {
        int i = base + t;
        uint32_t v = (i < NB) ? cnt[i] : 0u;
        lds[t] = v;
        __syncthreads();
        for (int off = 1; off < 1024; off <<= 1) {
            uint32_t add = (t >= off) ? lds[t - off] : 0u;
            __syncthreads();
            lds[t] += add;
            __syncthreads();
        }
        uint32_t incl  = lds[t];
        uint32_t total = lds[1023];
        uint32_t c     = s_carry;
        __syncthreads();
        if (i < NB) cnt[i] = incl - v + c;           // exclusive + carry
        if (t == 0) s_carry = c + total;
        __syncthreads();
    }
}

// partials[blk][b] := global start offset for block blk's edges of bucket b.
__global__ void bucket_offsets(uint32_t* __restrict__ partials,
                               const uint32_t* __restrict__ bstart) {
    int b = blockIdx.x * blockDim.x + threadIdx.x;
    if (b >= NB) return;
    uint32_t run = bstart[b];
    for (int blk = 0; blk < NBLK; ++blk) {
        size_t idx = (size_t)blk * NB + b;
        uint32_t t = partials[idx];
        partials[idx] = run;
        run += t;
    }
}

// Scatter edges into bucket-contiguous regions. No global atomics; LDS cursors only.
// Each (block,bucket) run averages 8 entries = 64B -> full-line writes.
__global__ __launch_bounds__(1024) void scatter_buckets(const int*   __restrict__ esrc,
                                                        const int*   __restrict__ edst,
                                                        const float* __restrict__ eval,
                                                        const uint32_t* __restrict__ partials,
                                                        int2* __restrict__ pairs) {
    __shared__ uint32_t cur[NB];
    int blk = blockIdx.x;
    for (int i = threadIdx.x; i < NB; i += 1024)
        cur[i] = partials[(size_t)blk * NB + i];
    __syncthreads();
    int e0 = blk * EPB;
    for (int i = threadIdx.x; i < EPB; i += 1024) {
        int e = e0 + i;
        int d = edst[e];
        int b = (uint32_t)d >> BSHIFT;
        uint32_t pos = atomicAdd(&cur[b], 1u);
        int packed = esrc[e] | ((d & (BNODES - 1)) << 18);   // src<2^18, dlow in [18,24)
        pairs[pos] = make_int2(packed, __float_as_int(eval[e]));
    }
}

// In-place per-bucket counting sort (one block per bucket; bucket staged in LDS).
// Also emits rowend[] for spmm_gather, killing the per-node hist + 200K scan.
__global__ __launch_bounds__(256) void bucket_sort(const uint32_t* __restrict__ bstart_arr,
                                                   int2* __restrict__ pairs,
                                                   uint32_t* __restrict__ rowend) {
    __shared__ int2 ebuf[BCAP];
    __shared__ uint32_t scnt[BNODES];
    int b = blockIdx.x;
    uint32_t start = bstart_arr[b];
    uint32_t end   = (b == NB - 1) ? (uint32_t)NNZ : bstart_arr[b + 1];
    int n = (int)(end - start);
    if (n > BCAP) n = BCAP;                          // safety clamp (statistically impossible)
    if (threadIdx.x < BNODES) scnt[threadIdx.x] = 0u;
    __syncthreads();
    for (int i = threadIdx.x; i < n; i += 256) {
        int2 e = pairs[start + i];
        ebuf[i] = e;
        atomicAdd(&scnt[(uint32_t)e.x >> 18], 1u);
    }
    __syncthreads();
    if (threadIdx.x < 64) {                          // wave 0: inclusive scan of 64 counters
        uint32_t c = scnt[threadIdx.x];
        uint32_t v = c;
        for (int off = 1; off < 64; off <<= 1) {
            uint32_t nv = __shfl_up(v, (unsigned)off, 64);
            if ((int)threadIdx.x >= off) v += nv;
        }
        rowend[b * BNODES + threadIdx.x] = start + v;   // global end offset per node
        scnt[threadIdx.x] = v - c;                      // exclusive -> write cursor
    }
    __syncthreads();
    for (int i = threadIdx.x; i < n; i += 256) {
        int2 e = ebuf[i];
        int dlow = (uint32_t)e.x >> 18;
        uint32_t pos = start + atomicAdd(&scnt[dlow], 1u);
        pairs[pos] = make_int2(e.x & 0x3FFFF, e.y);     // strip dlow bits
    }
}

// One wave per dst row; lane = column. No atomics. 4-edge unroll for MLP.
__global__ __launch_bounds__(256) void spmm_gather(const uint32_t* __restrict__ rowend,
                                                   const int2*     __restrict__ pairs,
                                                   const float*    __restrict__ prev,
                                                   float*          __restrict__ cur) {
    int w    = (blockIdx.x * blockDim.x + threadIdx.x) >> 6;  // row id
    int lane = threadIdx.x & 63;
    if (w >= NNODES) return;
    uint32_t start = (w == 0) ? 0u : rowend[w - 1];
    uint32_t end   = rowend[w];
    float acc = 0.f;
    uint32_t i = start;
    for (; i + 4 <= end; i += 4) {
        int2 p0 = pairs[i + 0];
        int2 p1 = pairs[i + 1];
        int2 p2 = pairs[i + 2];
        int2 p3 = pairs[i + 3];
        float x0 = prev[(size_t)p0.x * OUTDIM + lane];
        float x1 = prev[(size_t)p1.x * OUTDIM + lane];
        float x2 = prev[(size_t)p2.x * OUTDIM + lane];
        float x3 = prev[(size_t)p3.x * OUTDIM + lane];
        acc = fmaf(x0, __int_as_float(p0.y), acc);
        acc = fmaf(x1, __int_as_float(p1.y), acc);
        acc = fmaf(x2, __int_as_float(p2.y), acc);
        acc = fmaf(x3, __int_as_float(p3.y), acc);
    }
    for (; i < end; ++i) {
        int2 p = pairs[i];
        acc = fmaf(prev[(size_t)p.x * OUTDIM + lane], __int_as_float(p.y), acc);
    }
    cur[(size_t)w * OUTDIM + lane] = acc;
}

// ===================== OLD PATH (proven) for mid-size ws =====================

__global__ void zero_cnt(uint32_t* __restrict__ cnt) {
    int t = blockIdx.x * blockDim.x + threadIdx.x;
    if (t < NNODES) cnt[t] = 0u;
}

__global__ void hist(const int* __restrict__ edst, uint32_t* __restrict__ cnt) {
    int e = blockIdx.x * blockDim.x + threadIdx.x;
    if (e < NNZ) atomicAdd(&cnt[edst[e]], 1u);
}

__global__ __launch_bounds__(1024) void scan_cnt(uint32_t* __restrict__ cnt) {
    __shared__ uint32_t lds[1024];
    __shared__ uint32_t s_carry;
    int t = threadIdx.x;
    if (t == 0) s_carry = 0u;
    __syncthreads();
    for (int base = 0; base < NNODES; base += 1024) {
        int i = base + t;
        uint32_t v = (i < NNODES) ? cnt[i] : 0u;
        lds[t] = v;
        __syncthreads();
        for (int off = 1; off < 1024; off <<= 1) {
            uint32_t add = (t >= off) ? lds[t - off] : 0u;
            __syncthreads();
            lds[t] += add;
            __syncthreads();
        }
        uint32_t incl  = lds[t];
        uint32_t total = lds[1023];
        uint32_t c     = s_carry;
        __syncthreads();
        if (i < NNODES) cnt[i] = incl - v + c;
        if (t == 0) s_carry = c + total;
        __syncthreads();
    }
}

__global__ void fill_pairs(const int*   __restrict__ esrc,
                           const int*   __restrict__ edst,
                           const float* __restrict__ eval,
                           uint32_t*    __restrict__ cnt,
                           int2*        __restrict__ pairs) {
    int e = blockIdx.x * blockDim.x + threadIdx.x;
    if (e >= NNZ) return;
    int d = edst[e];
    uint32_t pos = atomicAdd(&cnt[d], 1u);
    pairs[pos] = make_int2(esrc[e], __float_as_int(eval[e]));
}

// ---------- fallback (atomics) if ws too small ----------
__global__ void init_out_full(const float* __restrict__ user_emb,
                              const float* __restrict__ item_emb,
                              float* __restrict__ out) {
    int t = blockIdx.x * blockDim.x + threadIdx.x;
    if (t >= NNODES * 64) return;
    int n = t >> 6;
    int c = (t & 63) << 2;
    float4 v = make_float4(0.f, 0.f, 0.f, 0.f);
    if (c < DIM) {
        const float* s = (n < U_NUM) ? (user_emb + (size_t)n * DIM + c)
                                     : (item_emb + (size_t)(n - U_NUM) * DIM + c);
        v = *(const float4*)s;
    }
    *(float4*)(out + (size_t)n * OUTDIM + c) = v;
}

__global__ void scatter_spmm(const int*   __restrict__ esrc,
                             const int*   __restrict__ edst,
                             const float* __restrict__ eval,
                             const float* __restrict__ prev,
                             float*       __restrict__ cur) {
    int t = blockIdx.x * blockDim.x + threadIdx.x;
    if (t >= NNZ * 16) return;
    int e = t >> 4;
    int j = (t & 15) << 2;
    int s = esrc[e];
    int d = edst[e];
    float v = eval[e];
    float4 x = *(const float4*)(prev + (size_t)s * OUTDIM + j);
    float* ap = cur + (size_t)d * OUTDIM + j;
    unsafeAtomicAdd(ap + 0, x.x * v);
    unsafeAtomicAdd(ap + 1, x.y * v);
    unsafeAtomicAdd(ap + 2, x.z * v);
    unsafeAtomicAdd(ap + 3, x.w * v);
}

extern "C" void kernel_launch(void* const* d_in, const int* in_sizes, int n_in,
                              void* d_out, int out_size, void* d_ws, size_t ws_size,
                              hipStream_t stream) {
    const float* user_emb = (const float*)d_in[0];
    const float* item_emb = (const float*)d_in[1];
    const float* eval     = (const float*)d_in[2];
    const int*   esrc     = (const int*)d_in[3];
    const int*   edst     = (const int*)d_in[4];
    float* out = (float*)d_out;                      // 200000 x 256 f32

    if (ws_size >= WS_NEEDED_NEW) {
        uint32_t* rowend   = (uint32_t*)((char*)d_ws + WS_ROWEND);
        int2*     pairs    = (int2*)   ((char*)d_ws + WS_PAIRS);
        uint32_t* bcnt     = (uint32_t*)((char*)d_ws + WS_BCNT);
        uint32_t* partials = (uint32_t*)((char*)d_ws + WS_PART);

        init_out<<<(NNODES * 16 + 255) / 256, 256, 0, stream>>>(user_emb, item_emb, out);
        bucket_hist<<<NBLK, 1024, 0, stream>>>(edst, partials);
        bucket_colsum<<<(NB + 255) / 256, 256, 0, stream>>>(partials, bcnt);
        scan_bcnt<<<1, 1024, 0, stream>>>(bcnt);
        bucket_offsets<<<(NB + 255) / 256, 256, 0, stream>>>(partials, bcnt);
        scatter_buckets<<<NBLK, 1024, 0, stream>>>(esrc, edst, eval, partials, pairs);
        bucket_sort<<<NB, 256, 0, stream>>>(bcnt, pairs, rowend);

        for (int l = 1; l <= 3; ++l) {
            spmm_gather<<<(NNODES * 64) / 256, 256, 0, stream>>>(
                rowend, pairs,
                out + (size_t)(l - 1) * DIM,
                out + (size_t)l * DIM);
        }
    } else if (ws_size >= WS_NEEDED_OLD) {
        uint32_t* cnt   = (uint32_t*)d_ws;
        int2*     pairs = (int2*)((char*)d_ws + 800000);

        init_out<<<(NNODES * 16 + 255) / 256, 256, 0, stream>>>(user_emb, item_emb, out);
        zero_cnt<<<(NNODES + 255) / 256, 256, 0, stream>>>(cnt);
        hist<<<NNZ / 256, 256, 0, stream>>>(edst, cnt);
        scan_cnt<<<1, 1024, 0, stream>>>(cnt);
        fill_pairs<<<NNZ / 256, 256, 0, stream>>>(esrc, edst, eval, cnt, pairs);

        for (int l = 1; l <= 3; ++l) {
            spmm_gather<<<(NNODES * 64) / 256, 256, 0, stream>>>(
                cnt, pairs,
                out + (size_t)(l - 1) * DIM,
                out + (size_t)l * DIM);
        }
    } else {
        init_out_full<<<(NNODES * 64 + 255) / 256, 256, 0, stream>>>(user_emb, item_emb, out);
        for (int l = 1; l <= 3; ++l) {
            scatter_spmm<<<(NNZ * 16) / 256, 256, 0, stream>>>(
                esrc, edst, eval,
                out + (size_t)(l - 1) * DIM,
                out + (size_t)l * DIM);
        }
    }
}

// Round 5
// 1245.852 us; speedup vs baseline: 1.5973x; 1.0074x over previous
//
#include <hip/hip_runtime.h>
#include <hip/hip_fp16.h>
#include <stdint.h>

#define U_NUM   100000
#define NNODES  200000
#define DIM     64
#define OUTDIM  256
#define NNZ     6400000

// ---- bucket decomposition ----
#define BSHIFT  6
#define BNODES  64                      // nodes per bucket (200000/64 = 3125 exact)
#define NB      (NNODES >> BSHIFT)      // 3125 buckets
#define BCAP    4096                    // LDS capacity per bucket (mean 2048, sd ~45)
#define NBLK    256                     // partition blocks
#define EPB     (NNZ / NBLK)            // 25000 edges per partition block

// ---------- ws layout ----------
// [0, 800000)                  : uint32 rowend (NNODES)
// [800000, 800000+NNZ*8)       : int2 pairs {packed_src_dlow | src, f32bits(val)}
// [52000000, +NB*4)            : uint32 bcnt (bucket counts -> exclusive starts)
// [52012500, +NBLK*NB*4)       : uint32 partials (per-block per-bucket offsets)
// [55220000, +25.6MB)          : fp16 mirror A (gather source)
// [80820000, +25.6MB)          : fp16 mirror B
#define WS_ROWEND    0
#define WS_PAIRS     800000
#define WS_BCNT      52000000
#define WS_PART      52012500
#define WS_NEEDED_NEW ((size_t)WS_PART + (size_t)NBLK * NB * 4)   // 55,212,500
#define WS_MIR0      55220000
#define WS_MIR1      (WS_MIR0 + (size_t)NNODES * DIM * 2)         // 80,820,000
#define WS_NEEDED_H  (WS_MIR1 + (size_t)NNODES * DIM * 2)         // 106,420,000
#define WS_NEEDED_OLD (800000 + (size_t)NNZ * 8)                  // 52,000,000

// Copy ego (user||item) into cols 0..63 of out (fp32). Layers 1..3 write 64..255.
__global__ void init_out(const float* __restrict__ user_emb,
                         const float* __restrict__ item_emb,
                         float* __restrict__ out) {
    int t = blockIdx.x * blockDim.x + threadIdx.x;   // NNODES*16 threads
    if (t >= NNODES * 16) return;
    int n = t >> 4;
    int c = (t & 15) << 2;
    const float* s = (n < U_NUM) ? (user_emb + (size_t)n * DIM + c)
                                 : (item_emb + (size_t)(n - U_NUM) * DIM + c);
    *(float4*)(out + (size_t)n * OUTDIM + c) = *(const float4*)s;
}

// Same, but also write an fp16 mirror of the ego slice (gather source for layer 1).
__global__ void init_out_h(const float* __restrict__ user_emb,
                           const float* __restrict__ item_emb,
                           float* __restrict__ out,
                           __half* __restrict__ mir) {
    int t = blockIdx.x * blockDim.x + threadIdx.x;   // NNODES*16 threads
    if (t >= NNODES * 16) return;
    int n = t >> 4;
    int c = (t & 15) << 2;
    const float* s = (n < U_NUM) ? (user_emb + (size_t)n * DIM + c)
                                 : (item_emb + (size_t)(n - U_NUM) * DIM + c);
    float4 v = *(const float4*)s;
    *(float4*)(out + (size_t)n * OUTDIM + c) = v;
    __half2 h01 = __floats2half2_rn(v.x, v.y);
    __half2 h23 = __floats2half2_rn(v.z, v.w);
    uint2 u;
    u.x = *(uint32_t*)&h01;
    u.y = *(uint32_t*)&h23;
    *(uint2*)(mir + (size_t)n * DIM + c) = u;
}

// ===================== radix partition (unchanged, proven) =====================

__global__ __launch_bounds__(1024) void bucket_hist(const int* __restrict__ edst,
                                                    uint32_t* __restrict__ partials) {
    __shared__ uint32_t h[NB];
    for (int i = threadIdx.x; i < NB; i += 1024) h[i] = 0u;
    __syncthreads();
    int blk = blockIdx.x;
    int e0 = blk * EPB;
    for (int i = threadIdx.x; i < EPB; i += 1024)
        atomicAdd(&h[(uint32_t)edst[e0 + i] >> BSHIFT], 1u);
    __syncthreads();
    for (int i = threadIdx.x; i < NB; i += 1024)
        partials[(size_t)blk * NB + i] = h[i];
}

__global__ void bucket_colsum(const uint32_t* __restrict__ partials,
                              uint32_t* __restrict__ bcnt) {
    int b = blockIdx.x * blockDim.x + threadIdx.x;
    if (b >= NB) return;
    uint32_t s = 0u;
    for (int blk = 0; blk < NBLK; ++blk) s += partials[(size_t)blk * NB + b];
    bcnt[b] = s;
}

__global__ __launch_bounds__(1024) void scan_bcnt(uint32_t* __restrict__ cnt) {
    __shared__ uint32_t lds[1024];
    __shared__ uint32_t s_carry;
    int t = threadIdx.x;
    if (t == 0) s_carry = 0u;
    __syncthreads();
    for (int base = 0; base < NB; base += 1024) {
        int i = base + t;
        uint32_t v = (i < NB) ? cnt[i] : 0u;
        lds[t] = v;
        __syncthreads();
        for (int off = 1; off < 1024; off <<= 1) {
            uint32_t add = (t >= off) ? lds[t - off] : 0u;
            __syncthreads();
            lds[t] += add;
            __syncthreads();
        }
        uint32_t incl  = lds[t];
        uint32_t total = lds[1023];
        uint32_t c     = s_carry;
        __syncthreads();
        if (i < NB) cnt[i] = incl - v + c;           // exclusive + carry
        if (t == 0) s_carry = c + total;
        __syncthreads();
    }
}

__global__ void bucket_offsets(uint32_t* __restrict__ partials,
                               const uint32_t* __restrict__ bstart) {
    int b = blockIdx.x * blockDim.x + threadIdx.x;
    if (b >= NB) return;
    uint32_t run = bstart[b];
    for (int blk = 0; blk < NBLK; ++blk) {
        size_t idx = (size_t)blk * NB + b;
        uint32_t t = partials[idx];
        partials[idx] = run;
        run += t;
    }
}

__global__ __launch_bounds__(1024) void scatter_buckets(const int*   __restrict__ esrc,
                                                        const int*   __restrict__ edst,
                                                        const float* __restrict__ eval,
                                                        const uint32_t* __restrict__ partials,
                                                        int2* __restrict__ pairs) {
    __shared__ uint32_t cur[NB];
    int blk = blockIdx.x;
    for (int i = threadIdx.x; i < NB; i += 1024)
        cur[i] = partials[(size_t)blk * NB + i];
    __syncthreads();
    int e0 = blk * EPB;
    for (int i = threadIdx.x; i < EPB; i += 1024) {
        int e = e0 + i;
        int d = edst[e];
        int b = (uint32_t)d >> BSHIFT;
        uint32_t pos = atomicAdd(&cur[b], 1u);
        int packed = esrc[e] | ((d & (BNODES - 1)) << 18);   // src<2^18, dlow in [18,24)
        pairs[pos] = make_int2(packed, __float_as_int(eval[e]));
    }
}

__global__ __launch_bounds__(256) void bucket_sort(const uint32_t* __restrict__ bstart_arr,
                                                   int2* __restrict__ pairs,
                                                   uint32_t* __restrict__ rowend) {
    __shared__ int2 ebuf[BCAP];
    __shared__ uint32_t scnt[BNODES];
    int b = blockIdx.x;
    uint32_t start = bstart_arr[b];
    uint32_t end   = (b == NB - 1) ? (uint32_t)NNZ : bstart_arr[b + 1];
    int n = (int)(end - start);
    if (n > BCAP) n = BCAP;                          // safety clamp
    if (threadIdx.x < BNODES) scnt[threadIdx.x] = 0u;
    __syncthreads();
    for (int i = threadIdx.x; i < n; i += 256) {
        int2 e = pairs[start + i];
        ebuf[i] = e;
        atomicAdd(&scnt[(uint32_t)e.x >> 18], 1u);
    }
    __syncthreads();
    if (threadIdx.x < 64) {                          // wave 0: inclusive scan of 64 counters
        uint32_t c = scnt[threadIdx.x];
        uint32_t v = c;
        for (int off = 1; off < 64; off <<= 1) {
            uint32_t nv = __shfl_up(v, (unsigned)off, 64);
            if ((int)threadIdx.x >= off) v += nv;
        }
        rowend[b * BNODES + threadIdx.x] = start + v;   // global end offset per node
        scnt[threadIdx.x] = v - c;                      // exclusive -> write cursor
    }
    __syncthreads();
    for (int i = threadIdx.x; i < n; i += 256) {
        int2 e = ebuf[i];
        int dlow = (uint32_t)e.x >> 18;
        uint32_t pos = start + atomicAdd(&scnt[dlow], 1u);
        pairs[pos] = make_int2(e.x & 0x3FFFF, e.y);     // strip dlow bits
    }
}

// ===================== gather SpMM =====================

// fp16-source variant: gather 128B/edge from fp16 mirror, fma in fp32,
// write fp32 out row + (optionally) the fp16 mirror for the next layer.
__global__ __launch_bounds__(256) void spmm_gather_h(const uint32_t* __restrict__ rowend,
                                                     const int2*     __restrict__ pairs,
                                                     const __half*   __restrict__ mirp,
                                                     float*          __restrict__ cur,
                                                     __half*         __restrict__ mirc) {
    int w    = (blockIdx.x * blockDim.x + threadIdx.x) >> 6;  // row id
    int lane = threadIdx.x & 63;
    if (w >= NNODES) return;
    uint32_t start = (w == 0) ? 0u : rowend[w - 1];
    uint32_t end   = rowend[w];
    float acc = 0.f;
    uint32_t i = start;
    for (; i + 4 <= end; i += 4) {
        int2 p0 = pairs[i + 0];
        int2 p1 = pairs[i + 1];
        int2 p2 = pairs[i + 2];
        int2 p3 = pairs[i + 3];
        float x0 = __half2float(mirp[(size_t)p0.x * DIM + lane]);
        float x1 = __half2float(mirp[(size_t)p1.x * DIM + lane]);
        float x2 = __half2float(mirp[(size_t)p2.x * DIM + lane]);
        float x3 = __half2float(mirp[(size_t)p3.x * DIM + lane]);
        acc = fmaf(x0, __int_as_float(p0.y), acc);
        acc = fmaf(x1, __int_as_float(p1.y), acc);
        acc = fmaf(x2, __int_as_float(p2.y), acc);
        acc = fmaf(x3, __int_as_float(p3.y), acc);
    }
    for (; i < end; ++i) {
        int2 p = pairs[i];
        acc = fmaf(__half2float(mirp[(size_t)p.x * DIM + lane]), __int_as_float(p.y), acc);
    }
    cur[(size_t)w * OUTDIM + lane] = acc;
    if (mirc) mirc[(size_t)w * DIM + lane] = __float2half(acc);
}

// fp32-source variant (proven R1 path).
__global__ __launch_bounds__(256) void spmm_gather(const uint32_t* __restrict__ rowend,
                                                   const int2*     __restrict__ pairs,
                                                   const float*    __restrict__ prev,
                                                   float*          __restrict__ cur) {
    int w    = (blockIdx.x * blockDim.x + threadIdx.x) >> 6;  // row id
    int lane = threadIdx.x & 63;
    if (w >= NNODES) return;
    uint32_t start = (w == 0) ? 0u : rowend[w - 1];
    uint32_t end   = rowend[w];
    float acc = 0.f;
    uint32_t i = start;
    for (; i + 4 <= end; i += 4) {
        int2 p0 = pairs[i + 0];
        int2 p1 = pairs[i + 1];
        int2 p2 = pairs[i + 2];
        int2 p3 = pairs[i + 3];
        float x0 = prev[(size_t)p0.x * OUTDIM + lane];
        float x1 = prev[(size_t)p1.x * OUTDIM + lane];
        float x2 = prev[(size_t)p2.x * OUTDIM + lane];
        float x3 = prev[(size_t)p3.x * OUTDIM + lane];
        acc = fmaf(x0, __int_as_float(p0.y), acc);
        acc = fmaf(x1, __int_as_float(p1.y), acc);
        acc = fmaf(x2, __int_as_float(p2.y), acc);
        acc = fmaf(x3, __int_as_float(p3.y), acc);
    }
    for (; i < end; ++i) {
        int2 p = pairs[i];
        acc = fmaf(prev[(size_t)p.x * OUTDIM + lane], __int_as_float(p.y), acc);
    }
    cur[(size_t)w * OUTDIM + lane] = acc;
}

// ===================== OLD PATH helpers (proven) =====================

__global__ void zero_cnt(uint32_t* __restrict__ cnt) {
    int t = blockIdx.x * blockDim.x + threadIdx.x;
    if (t < NNODES) cnt[t] = 0u;
}

__global__ void hist(const int* __restrict__ edst, uint32_t* __restrict__ cnt) {
    int e = blockIdx.x * blockDim.x + threadIdx.x;
    if (e < NNZ) atomicAdd(&cnt[edst[e]], 1u);
}

__global__ __launch_bounds__(1024) void scan_cnt(uint32_t* __restrict__ cnt) {
    __shared__ uint32_t lds[1024];
    __shared__ uint32_t s_carry;
    int t = threadIdx.x;
    if (t == 0) s_carry = 0u;
    __syncthreads();
    for (int base = 0; base < NNODES; base += 1024) {
        int i = base + t;
        uint32_t v = (i < NNODES) ? cnt[i] : 0u;
        lds[t] = v;
        __syncthreads();
        for (int off = 1; off < 1024; off <<= 1) {
            uint32_t add = (t >= off) ? lds[t - off] : 0u;
            __syncthreads();
            lds[t] += add;
            __syncthreads();
        }
        uint32_t incl  = lds[t];
        uint32_t total = lds[1023];
        uint32_t c     = s_carry;
        __syncthreads();
        if (i < NNODES) cnt[i] = incl - v + c;
        if (t == 0) s_carry = c + total;
        __syncthreads();
    }
}

__global__ void fill_pairs(const int*   __restrict__ esrc,
                           const int*   __restrict__ edst,
                           const float* __restrict__ eval,
                           uint32_t*    __restrict__ cnt,
                           int2*        __restrict__ pairs) {
    int e = blockIdx.x * blockDim.x + threadIdx.x;
    if (e >= NNZ) return;
    int d = edst[e];
    uint32_t pos = atomicAdd(&cnt[d], 1u);
    pairs[pos] = make_int2(esrc[e], __float_as_int(eval[e]));
}

// ---------- fallback (atomics) if ws too small ----------
__global__ void init_out_full(const float* __restrict__ user_emb,
                              const float* __restrict__ item_emb,
                              float* __restrict__ out) {
    int t = blockIdx.x * blockDim.x + threadIdx.x;
    if (t >= NNODES * 64) return;
    int n = t >> 6;
    int c = (t & 63) << 2;
    float4 v = make_float4(0.f, 0.f, 0.f, 0.f);
    if (c < DIM) {
        const float* s = (n < U_NUM) ? (user_emb + (size_t)n * DIM + c)
                                     : (item_emb + (size_t)(n - U_NUM) * DIM + c);
        v = *(const float4*)s;
    }
    *(float4*)(out + (size_t)n * OUTDIM + c) = v;
}

__global__ void scatter_spmm(const int*   __restrict__ esrc,
                             const int*   __restrict__ edst,
                             const float* __restrict__ eval,
                             const float* __restrict__ prev,
                             float*       __restrict__ cur) {
    int t = blockIdx.x * blockDim.x + threadIdx.x;
    if (t >= NNZ * 16) return;
    int e = t >> 4;
    int j = (t & 15) << 2;
    int s = esrc[e];
    int d = edst[e];
    float v = eval[e];
    float4 x = *(const float4*)(prev + (size_t)s * OUTDIM + j);
    float* ap = cur + (size_t)d * OUTDIM + j;
    unsafeAtomicAdd(ap + 0, x.x * v);
    unsafeAtomicAdd(ap + 1, x.y * v);
    unsafeAtomicAdd(ap + 2, x.z * v);
    unsafeAtomicAdd(ap + 3, x.w * v);
}

extern "C" void kernel_launch(void* const* d_in, const int* in_sizes, int n_in,
                              void* d_out, int out_size, void* d_ws, size_t ws_size,
                              hipStream_t stream) {
    const float* user_emb = (const float*)d_in[0];
    const float* item_emb = (const float*)d_in[1];
    const float* eval     = (const float*)d_in[2];
    const int*   esrc     = (const int*)d_in[3];
    const int*   edst     = (const int*)d_in[4];
    float* out = (float*)d_out;                      // 200000 x 256 f32

    if (ws_size >= WS_NEEDED_H) {
        // ---- fp16-mirror path ----
        uint32_t* rowend   = (uint32_t*)((char*)d_ws + WS_ROWEND);
        int2*     pairs    = (int2*)   ((char*)d_ws + WS_PAIRS);
        uint32_t* bcnt     = (uint32_t*)((char*)d_ws + WS_BCNT);
        uint32_t* partials = (uint32_t*)((char*)d_ws + WS_PART);
        __half*   mir0     = (__half*) ((char*)d_ws + WS_MIR0);
        __half*   mir1     = (__half*) ((char*)d_ws + WS_MIR1);

        init_out_h<<<(NNODES * 16 + 255) / 256, 256, 0, stream>>>(user_emb, item_emb, out, mir0);
        bucket_hist<<<NBLK, 1024, 0, stream>>>(edst, partials);
        bucket_colsum<<<(NB + 255) / 256, 256, 0, stream>>>(partials, bcnt);
        scan_bcnt<<<1, 1024, 0, stream>>>(bcnt);
        bucket_offsets<<<(NB + 255) / 256, 256, 0, stream>>>(partials, bcnt);
        scatter_buckets<<<NBLK, 1024, 0, stream>>>(esrc, edst, eval, partials, pairs);
        bucket_sort<<<NB, 256, 0, stream>>>(bcnt, pairs, rowend);

        // layer1: mir0 -> out[64..127] + mir1
        spmm_gather_h<<<(NNODES * 64) / 256, 256, 0, stream>>>(
            rowend, pairs, mir0, out + (size_t)1 * DIM, mir1);
        // layer2: mir1 -> out[128..191] + mir0 (ego mirror no longer needed)
        spmm_gather_h<<<(NNODES * 64) / 256, 256, 0, stream>>>(
            rowend, pairs, mir1, out + (size_t)2 * DIM, mir0);
        // layer3: mir0 -> out[192..255], no mirror write
        spmm_gather_h<<<(NNODES * 64) / 256, 256, 0, stream>>>(
            rowend, pairs, mir0, out + (size_t)3 * DIM, (__half*)nullptr);
    } else if (ws_size >= WS_NEEDED_NEW) {
        // ---- R1 proven fp32 path ----
        uint32_t* rowend   = (uint32_t*)((char*)d_ws + WS_ROWEND);
        int2*     pairs    = (int2*)   ((char*)d_ws + WS_PAIRS);
        uint32_t* bcnt     = (uint32_t*)((char*)d_ws + WS_BCNT);
        uint32_t* partials = (uint32_t*)((char*)d_ws + WS_PART);

        init_out<<<(NNODES * 16 + 255) / 256, 256, 0, stream>>>(user_emb, item_emb, out);
        bucket_hist<<<NBLK, 1024, 0, stream>>>(edst, partials);
        bucket_colsum<<<(NB + 255) / 256, 256, 0, stream>>>(partials, bcnt);
        scan_bcnt<<<1, 1024, 0, stream>>>(bcnt);
        bucket_offsets<<<(NB + 255) / 256, 256, 0, stream>>>(partials, bcnt);
        scatter_buckets<<<NBLK, 1024, 0, stream>>>(esrc, edst, eval, partials, pairs);
        bucket_sort<<<NB, 256, 0, stream>>>(bcnt, pairs, rowend);

        for (int l = 1; l <= 3; ++l) {
            spmm_gather<<<(NNODES * 64) / 256, 256, 0, stream>>>(
                rowend, pairs,
                out + (size_t)(l - 1) * DIM,
                out + (size_t)l * DIM);
        }
    } else if (ws_size >= WS_NEEDED_OLD) {
        uint32_t* cnt   = (uint32_t*)d_ws;
        int2*     pairs = (int2*)((char*)d_ws + 800000);

        init_out<<<(NNODES * 16 + 255) / 256, 256, 0, stream>>>(user_emb, item_emb, out);
        zero_cnt<<<(NNODES + 255) / 256, 256, 0, stream>>>(cnt);
        hist<<<NNZ / 256, 256, 0, stream>>>(edst, cnt);
        scan_cnt<<<1, 1024, 0, stream>>>(cnt);
        fill_pairs<<<NNZ / 256, 256, 0, stream>>>(esrc, edst, eval, cnt, pairs);

        for (int l = 1; l <= 3; ++l) {
            spmm_gather<<<(NNODES * 64) / 256, 256, 0, stream>>>(
                cnt, pairs,
                out + (size_t)(l - 1) * DIM,
                out + (size_t)l * DIM);
        }
    } else {
        init_out_full<<<(NNODES * 64 + 255) / 256, 256, 0, stream>>>(user_emb, item_emb, out);
        for (int l = 1; l <= 3; ++l) {
            scatter_spmm<<<(NNZ * 16) / 256, 256, 0, stream>>>(
                esrc, edst, eval,
                out + (size_t)(l - 1) * DIM,
                out + (size_t)l * DIM);
        }
    }
}

// Round 9
// 1093.288 us; speedup vs baseline: 1.8202x; 1.1395x over previous
//
#include <hip/hip_runtime.h>
#include <hip/hip_fp16.h>
#include <stdint.h>

#define U_NUM   100000
#define NNODES  200000
#define DIM     64
#define OUTDIM  256
#define NNZ     6400000

// ---- bucket decomposition ----
#define BSHIFT  6
#define BNODES  64                      // nodes per bucket (200000/64 = 3125 exact)
#define NB      (NNODES >> BSHIFT)      // 3125 buckets
#define BCAP    4096                    // LDS capacity per bucket (mean 2048, sd ~45)
#define NBLK    256                     // partition blocks
#define EPB     (NNZ / NBLK)            // 25000 edges per partition block

// ---------- ws layout ----------
// [0, 800000)                  : uint32 rowend (NNODES)
// [800000, 800000+NNZ*8)       : int2 pairs {packed_src_dlow | src, f32bits(val)}
// [52000000, +NB*4)            : uint32 bcnt (bucket counts -> exclusive starts)
// [52012500, +NBLK*NB*4)       : uint32 partials (per-block per-bucket offsets)
// [55220000, +25.6MB)          : fp16 mirror A (gather source)
// [80820000, +25.6MB)          : fp16 mirror B
#define WS_ROWEND    0
#define WS_PAIRS     800000
#define WS_BCNT      52000000
#define WS_PART      52012500
#define WS_NEEDED_NEW ((size_t)WS_PART + (size_t)NBLK * NB * 4)   // 55,212,500
#define WS_MIR0      55220000
#define WS_MIR1      (WS_MIR0 + (size_t)NNODES * DIM * 2)         // 80,820,000
#define WS_NEEDED_H  (WS_MIR1 + (size_t)NNODES * DIM * 2)         // 106,420,000
#define WS_NEEDED_OLD (800000 + (size_t)NNZ * 8)                  // 52,000,000

// Copy ego (user||item) into cols 0..63 of out (fp32). Layers 1..3 write 64..255.
__global__ void init_out(const float* __restrict__ user_emb,
                         const float* __restrict__ item_emb,
                         float* __restrict__ out) {
    int t = blockIdx.x * blockDim.x + threadIdx.x;   // NNODES*16 threads
    if (t >= NNODES * 16) return;
    int n = t >> 4;
    int c = (t & 15) << 2;
    const float* s = (n < U_NUM) ? (user_emb + (size_t)n * DIM + c)
                                 : (item_emb + (size_t)(n - U_NUM) * DIM + c);
    *(float4*)(out + (size_t)n * OUTDIM + c) = *(const float4*)s;
}

// Same, but also write an fp16 mirror of the ego slice (gather source for layer 1).
__global__ void init_out_h(const float* __restrict__ user_emb,
                           const float* __restrict__ item_emb,
                           float* __restrict__ out,
                           __half* __restrict__ mir) {
    int t = blockIdx.x * blockDim.x + threadIdx.x;   // NNODES*16 threads
    if (t >= NNODES * 16) return;
    int n = t >> 4;
    int c = (t & 15) << 2;
    const float* s = (n < U_NUM) ? (user_emb + (size_t)n * DIM + c)
                                 : (item_emb + (size_t)(n - U_NUM) * DIM + c);
    float4 v = *(const float4*)s;
    *(float4*)(out + (size_t)n * OUTDIM + c) = v;
    __half2 h01 = __floats2half2_rn(v.x, v.y);
    __half2 h23 = __floats2half2_rn(v.z, v.w);
    uint2 u;
    u.x = *(uint32_t*)&h01;
    u.y = *(uint32_t*)&h23;
    *(uint2*)(mir + (size_t)n * DIM + c) = u;
}

// ===================== radix partition (unchanged, proven) =====================

__global__ __launch_bounds__(1024) void bucket_hist(const int* __restrict__ edst,
                                                    uint32_t* __restrict__ partials) {
    __shared__ uint32_t h[NB];
    for (int i = threadIdx.x; i < NB; i += 1024) h[i] = 0u;
    __syncthreads();
    int blk = blockIdx.x;
    int e0 = blk * EPB;
    for (int i = threadIdx.x; i < EPB; i += 1024)
        atomicAdd(&h[(uint32_t)edst[e0 + i] >> BSHIFT], 1u);
    __syncthreads();
    for (int i = threadIdx.x; i < NB; i += 1024)
        partials[(size_t)blk * NB + i] = h[i];
}

__global__ void bucket_colsum(const uint32_t* __restrict__ partials,
                              uint32_t* __restrict__ bcnt) {
    int b = blockIdx.x * blockDim.x + threadIdx.x;
    if (b >= NB) return;
    uint32_t s = 0u;
    for (int blk = 0; blk < NBLK; ++blk) s += partials[(size_t)blk * NB + b];
    bcnt[b] = s;
}

__global__ __launch_bounds__(1024) void scan_bcnt(uint32_t* __restrict__ cnt) {
    __shared__ uint32_t lds[1024];
    __shared__ uint32_t s_carry;
    int t = threadIdx.x;
    if (t == 0) s_carry = 0u;
    __syncthreads();
    for (int base = 0; base < NB; base += 1024) {
        int i = base + t;
        uint32_t v = (i < NB) ? cnt[i] : 0u;
        lds[t] = v;
        __syncthreads();
        for (int off = 1; off < 1024; off <<= 1) {
            uint32_t add = (t >= off) ? lds[t - off] : 0u;
            __syncthreads();
            lds[t] += add;
            __syncthreads();
        }
        uint32_t incl  = lds[t];
        uint32_t total = lds[1023];
        uint32_t c     = s_carry;
        __syncthreads();
        if (i < NB) cnt[i] = incl - v + c;           // exclusive + carry
        if (t == 0) s_carry = c + total;
        __syncthreads();
    }
}

__global__ void bucket_offsets(uint32_t* __restrict__ partials,
                               const uint32_t* __restrict__ bstart) {
    int b = blockIdx.x * blockDim.x + threadIdx.x;
    if (b >= NB) return;
    uint32_t run = bstart[b];
    for (int blk = 0; blk < NBLK; ++blk) {
        size_t idx = (size_t)blk * NB + b;
        uint32_t t = partials[idx];
        partials[idx] = run;
        run += t;
    }
}

__global__ __launch_bounds__(1024) void scatter_buckets(const int*   __restrict__ esrc,
                                                        const int*   __restrict__ edst,
                                                        const float* __restrict__ eval,
                                                        const uint32_t* __restrict__ partials,
                                                        int2* __restrict__ pairs) {
    __shared__ uint32_t cur[NB];
    int blk = blockIdx.x;
    for (int i = threadIdx.x; i < NB; i += 1024)
        cur[i] = partials[(size_t)blk * NB + i];
    __syncthreads();
    int e0 = blk * EPB;
    for (int i = threadIdx.x; i < EPB; i += 1024) {
        int e = e0 + i;
        int d = edst[e];
        int b = (uint32_t)d >> BSHIFT;
        uint32_t pos = atomicAdd(&cur[b], 1u);
        int packed = esrc[e] | ((d & (BNODES - 1)) << 18);   // src<2^18, dlow in [18,24)
        pairs[pos] = make_int2(packed, __float_as_int(eval[e]));
    }
}

__global__ __launch_bounds__(256) void bucket_sort(const uint32_t* __restrict__ bstart_arr,
                                                   int2* __restrict__ pairs,
                                                   uint32_t* __restrict__ rowend) {
    __shared__ int2 ebuf[BCAP];
    __shared__ uint32_t scnt[BNODES];
    int b = blockIdx.x;
    uint32_t start = bstart_arr[b];
    uint32_t end   = (b == NB - 1) ? (uint32_t)NNZ : bstart_arr[b + 1];
    int n = (int)(end - start);
    if (n > BCAP) n = BCAP;                          // safety clamp
    if (threadIdx.x < BNODES) scnt[threadIdx.x] = 0u;
    __syncthreads();
    for (int i = threadIdx.x; i < n; i += 256) {
        int2 e = pairs[start + i];
        ebuf[i] = e;
        atomicAdd(&scnt[(uint32_t)e.x >> 18], 1u);
    }
    __syncthreads();
    if (threadIdx.x < 64) {                          // wave 0: inclusive scan of 64 counters
        uint32_t c = scnt[threadIdx.x];
        uint32_t v = c;
        for (int off = 1; off < 64; off <<= 1) {
            uint32_t nv = __shfl_up(v, (unsigned)off, 64);
            if ((int)threadIdx.x >= off) v += nv;
        }
        rowend[b * BNODES + threadIdx.x] = start + v;   // global end offset per node
        scnt[threadIdx.x] = v - c;                      // exclusive -> write cursor
    }
    __syncthreads();
    for (int i = threadIdx.x; i < n; i += 256) {
        int2 e = ebuf[i];
        int dlow = (uint32_t)e.x >> 18;
        uint32_t pos = start + atomicAdd(&scnt[dlow], 1u);
        pairs[pos] = make_int2(e.x & 0x3FFFF, e.y);     // strip dlow bits
    }
}

// ===================== gather SpMM =====================

// 8-edges-per-instruction fp16 gather. Lane layout: g = lane>>3 (edge slot 0..7),
// l = lane&7 (column octet: cols 8l..8l+7). Each lane loads 16B (half8) of its
// edge-slot's source row; one wave-instruction gathers 8 edges. Per row of avg
// 32 edges: 4 gather instructions instead of 32 -> 8x less latency exposure.
// Cross-slot combine: 3 shfl_xor steps (8,16,32).
__global__ __launch_bounds__(256) void spmm_gather_h8(const uint32_t* __restrict__ rowend,
                                                      const int2*     __restrict__ pairs,
                                                      const __half*   __restrict__ mirp,
                                                      float*          __restrict__ cur,
                                                      __half*         __restrict__ mirc) {
    int w    = (blockIdx.x * blockDim.x + threadIdx.x) >> 6;  // row id
    int lane = threadIdx.x & 63;
    if (w >= NNODES) return;
    uint32_t start = (w == 0) ? 0u : rowend[w - 1];
    uint32_t end   = rowend[w];
    int g = lane >> 3;                    // edge slot 0..7
    int l = lane & 7;                     // column octet 0..7

    float acc0 = 0.f, acc1 = 0.f, acc2 = 0.f, acc3 = 0.f;
    float acc4 = 0.f, acc5 = 0.f, acc6 = 0.f, acc7 = 0.f;

    for (uint32_t i = start; i < end; i += 8) {
        uint32_t idx = i + (uint32_t)g;
        int2 p = (idx < end) ? pairs[idx] : make_int2(0, 0);   // dummy: row 0, val 0
        const uint4* rp = (const uint4*)(mirp + (size_t)p.x * DIM) + l;
        uint4 hv = *rp;                   // 8 halves = 16B
        float v = __int_as_float(p.y);
        __half2 h0 = *(__half2*)&hv.x;
        __half2 h1 = *(__half2*)&hv.y;
        __half2 h2 = *(__half2*)&hv.z;
        __half2 h3 = *(__half2*)&hv.w;
        float2 f0 = __half22float2(h0);
        float2 f1 = __half22float2(h1);
        float2 f2 = __half22float2(h2);
        float2 f3 = __half22float2(h3);
        acc0 = fmaf(f0.x, v, acc0);
        acc1 = fmaf(f0.y, v, acc1);
        acc2 = fmaf(f1.x, v, acc2);
        acc3 = fmaf(f1.y, v, acc3);
        acc4 = fmaf(f2.x, v, acc4);
        acc5 = fmaf(f2.y, v, acc5);
        acc6 = fmaf(f3.x, v, acc6);
        acc7 = fmaf(f3.y, v, acc7);
    }

    // combine the 8 edge slots (lane bits 3..5)
    #pragma unroll
    for (int off = 8; off < 64; off <<= 1) {
        acc0 += __shfl_xor(acc0, off, 64);
        acc1 += __shfl_xor(acc1, off, 64);
        acc2 += __shfl_xor(acc2, off, 64);
        acc3 += __shfl_xor(acc3, off, 64);
        acc4 += __shfl_xor(acc4, off, 64);
        acc5 += __shfl_xor(acc5, off, 64);
        acc6 += __shfl_xor(acc6, off, 64);
        acc7 += __shfl_xor(acc7, off, 64);
    }

    if (lane < 8) {                       // g==0 lanes hold cols 8l..8l+7
        float* op = cur + (size_t)w * OUTDIM + 8 * l;
        *(float4*)(op + 0) = make_float4(acc0, acc1, acc2, acc3);
        *(float4*)(op + 4) = make_float4(acc4, acc5, acc6, acc7);
        if (mirc) {
            __half2 a0 = __floats2half2_rn(acc0, acc1);
            __half2 a1 = __floats2half2_rn(acc2, acc3);
            __half2 a2 = __floats2half2_rn(acc4, acc5);
            __half2 a3 = __floats2half2_rn(acc6, acc7);
            uint4 u;
            u.x = *(uint32_t*)&a0;
            u.y = *(uint32_t*)&a1;
            u.z = *(uint32_t*)&a2;
            u.w = *(uint32_t*)&a3;
            *(uint4*)(mirc + (size_t)w * DIM + 8 * l) = u;
        }
    }
}

// fp32-source variant (proven R1 path, mid-tier fallback).
__global__ __launch_bounds__(256) void spmm_gather(const uint32_t* __restrict__ rowend,
                                                   const int2*     __restrict__ pairs,
                                                   const float*    __restrict__ prev,
                                                   float*          __restrict__ cur) {
    int w    = (blockIdx.x * blockDim.x + threadIdx.x) >> 6;  // row id
    int lane = threadIdx.x & 63;
    if (w >= NNODES) return;
    uint32_t start = (w == 0) ? 0u : rowend[w - 1];
    uint32_t end   = rowend[w];
    float acc = 0.f;
    uint32_t i = start;
    for (; i + 4 <= end; i += 4) {
        int2 p0 = pairs[i + 0];
        int2 p1 = pairs[i + 1];
        int2 p2 = pairs[i + 2];
        int2 p3 = pairs[i + 3];
        float x0 = prev[(size_t)p0.x * OUTDIM + lane];
        float x1 = prev[(size_t)p1.x * OUTDIM + lane];
        float x2 = prev[(size_t)p2.x * OUTDIM + lane];
        float x3 = prev[(size_t)p3.x * OUTDIM + lane];
        acc = fmaf(x0, __int_as_float(p0.y), acc);
        acc = fmaf(x1, __int_as_float(p1.y), acc);
        acc = fmaf(x2, __int_as_float(p2.y), acc);
        acc = fmaf(x3, __int_as_float(p3.y), acc);
    }
    for (; i < end; ++i) {
        int2 p = pairs[i];
        acc = fmaf(prev[(size_t)p.x * OUTDIM + lane], __int_as_float(p.y), acc);
    }
    cur[(size_t)w * OUTDIM + lane] = acc;
}

// ===================== OLD PATH helpers (proven) =====================

__global__ void zero_cnt(uint32_t* __restrict__ cnt) {
    int t = blockIdx.x * blockDim.x + threadIdx.x;
    if (t < NNODES) cnt[t] = 0u;
}

__global__ void hist(const int* __restrict__ edst, uint32_t* __restrict__ cnt) {
    int e = blockIdx.x * blockDim.x + threadIdx.x;
    if (e < NNZ) atomicAdd(&cnt[edst[e]], 1u);
}

__global__ __launch_bounds__(1024) void scan_cnt(uint32_t* __restrict__ cnt) {
    __shared__ uint32_t lds[1024];
    __shared__ uint32_t s_carry;
    int t = threadIdx.x;
    if (t == 0) s_carry = 0u;
    __syncthreads();
    for (int base = 0; base < NNODES; base += 1024) {
        int i = base + t;
        uint32_t v = (i < NNODES) ? cnt[i] : 0u;
        lds[t] = v;
        __syncthreads();
        for (int off = 1; off < 1024; off <<= 1) {
            uint32_t add = (t >= off) ? lds[t - off] : 0u;
            __syncthreads();
            lds[t] += add;
            __syncthreads();
        }
        uint32_t incl  = lds[t];
        uint32_t total = lds[1023];
        uint32_t c     = s_carry;
        __syncthreads();
        if (i < NNODES) cnt[i] = incl - v + c;
        if (t == 0) s_carry = c + total;
        __syncthreads();
    }
}

__global__ void fill_pairs(const int*   __restrict__ esrc,
                           const int*   __restrict__ edst,
                           const float* __restrict__ eval,
                           uint32_t*    __restrict__ cnt,
                           int2*        __restrict__ pairs) {
    int e = blockIdx.x * blockDim.x + threadIdx.x;
    if (e >= NNZ) return;
    int d = edst[e];
    uint32_t pos = atomicAdd(&cnt[d], 1u);
    pairs[pos] = make_int2(esrc[e], __float_as_int(eval[e]));
}

// ---------- fallback (atomics) if ws too small ----------
__global__ void init_out_full(const float* __restrict__ user_emb,
                              const float* __restrict__ item_emb,
                              float* __restrict__ out) {
    int t = blockIdx.x * blockDim.x + threadIdx.x;
    if (t >= NNODES * 64) return;
    int n = t >> 6;
    int c = (t & 63) << 2;
    float4 v = make_float4(0.f, 0.f, 0.f, 0.f);
    if (c < DIM) {
        const float* s = (n < U_NUM) ? (user_emb + (size_t)n * DIM + c)
                                     : (item_emb + (size_t)(n - U_NUM) * DIM + c);
        v = *(const float4*)s;
    }
    *(float4*)(out + (size_t)n * OUTDIM + c) = v;
}

__global__ void scatter_spmm(const int*   __restrict__ esrc,
                             const int*   __restrict__ edst,
                             const float* __restrict__ eval,
                             const float* __restrict__ prev,
                             float*       __restrict__ cur) {
    int t = blockIdx.x * blockDim.x + threadIdx.x;
    if (t >= NNZ * 16) return;
    int e = t >> 4;
    int j = (t & 15) << 2;
    int s = esrc[e];
    int d = edst[e];
    float v = eval[e];
    float4 x = *(const float4*)(prev + (size_t)s * OUTDIM + j);
    float* ap = cur + (size_t)d * OUTDIM + j;
    unsafeAtomicAdd(ap + 0, x.x * v);
    unsafeAtomicAdd(ap + 1, x.y * v);
    unsafeAtomicAdd(ap + 2, x.z * v);
    unsafeAtomicAdd(ap + 3, x.w * v);
}

extern "C" void kernel_launch(void* const* d_in, const int* in_sizes, int n_in,
                              void* d_out, int out_size, void* d_ws, size_t ws_size,
                              hipStream_t stream) {
    const float* user_emb = (const float*)d_in[0];
    const float* item_emb = (const float*)d_in[1];
    const float* eval     = (const float*)d_in[2];
    const int*   esrc     = (const int*)d_in[3];
    const int*   edst     = (const int*)d_in[4];
    float* out = (float*)d_out;                      // 200000 x 256 f32

    if (ws_size >= WS_NEEDED_H) {
        // ---- fp16-mirror path, 8-edge gather ----
        uint32_t* rowend   = (uint32_t*)((char*)d_ws + WS_ROWEND);
        int2*     pairs    = (int2*)   ((char*)d_ws + WS_PAIRS);
        uint32_t* bcnt     = (uint32_t*)((char*)d_ws + WS_BCNT);
        uint32_t* partials = (uint32_t*)((char*)d_ws + WS_PART);
        __half*   mir0     = (__half*) ((char*)d_ws + WS_MIR0);
        __half*   mir1     = (__half*) ((char*)d_ws + WS_MIR1);

        init_out_h<<<(NNODES * 16 + 255) / 256, 256, 0, stream>>>(user_emb, item_emb, out, mir0);
        bucket_hist<<<NBLK, 1024, 0, stream>>>(edst, partials);
        bucket_colsum<<<(NB + 255) / 256, 256, 0, stream>>>(partials, bcnt);
        scan_bcnt<<<1, 1024, 0, stream>>>(bcnt);
        bucket_offsets<<<(NB + 255) / 256, 256, 0, stream>>>(partials, bcnt);
        scatter_buckets<<<NBLK, 1024, 0, stream>>>(esrc, edst, eval, partials, pairs);
        bucket_sort<<<NB, 256, 0, stream>>>(bcnt, pairs, rowend);

        // layer1: mir0 -> out[64..127] + mir1
        spmm_gather_h8<<<(NNODES * 64) / 256, 256, 0, stream>>>(
            rowend, pairs, mir0, out + (size_t)1 * DIM, mir1);
        // layer2: mir1 -> out[128..191] + mir0
        spmm_gather_h8<<<(NNODES * 64) / 256, 256, 0, stream>>>(
            rowend, pairs, mir1, out + (size_t)2 * DIM, mir0);
        // layer3: mir0 -> out[192..255], no mirror write
        spmm_gather_h8<<<(NNODES * 64) / 256, 256, 0, stream>>>(
            rowend, pairs, mir0, out + (size_t)3 * DIM, (__half*)nullptr);
    } else if (ws_size >= WS_NEEDED_NEW) {
        // ---- R1 proven fp32 path ----
        uint32_t* rowend   = (uint32_t*)((char*)d_ws + WS_ROWEND);
        int2*     pairs    = (int2*)   ((char*)d_ws + WS_PAIRS);
        uint32_t* bcnt     = (uint32_t*)((char*)d_ws + WS_BCNT);
        uint32_t* partials = (uint32_t*)((char*)d_ws + WS_PART);

        init_out<<<(NNODES * 16 + 255) / 256, 256, 0, stream>>>(user_emb, item_emb, out);
        bucket_hist<<<NBLK, 1024, 0, stream>>>(edst, partials);
        bucket_colsum<<<(NB + 255) / 256, 256, 0, stream>>>(partials, bcnt);
        scan_bcnt<<<1, 1024, 0, stream>>>(bcnt);
        bucket_offsets<<<(NB + 255) / 256, 256, 0, stream>>>(partials, bcnt);
        scatter_buckets<<<NBLK, 1024, 0, stream>>>(esrc, edst, eval, partials, pairs);
        bucket_sort<<<NB, 256, 0, stream>>>(bcnt, pairs, rowend);

        for (int l = 1; l <= 3; ++l) {
            spmm_gather<<<(NNODES * 64) / 256, 256, 0, stream>>>(
                rowend, pairs,
                out + (size_t)(l - 1) * DIM,
                out + (size_t)l * DIM);
        }
    } else if (ws_size >= WS_NEEDED_OLD) {
        uint32_t* cnt   = (uint32_t*)d_ws;
        int2*     pairs = (int2*)((char*)d_ws + 800000);

        init_out<<<(NNODES * 16 + 255) / 256, 256, 0, stream>>>(user_emb, item_emb, out);
        zero_cnt<<<(NNODES + 255) / 256, 256, 0, stream>>>(cnt);
        hist<<<NNZ / 256, 256, 0, stream>>>(edst, cnt);
        scan_cnt<<<1, 1024, 0, stream>>>(cnt);
        fill_pairs<<<NNZ / 256, 256, 0, stream>>>(esrc, edst, eval, cnt, pairs);

        for (int l = 1; l <= 3; ++l) {
            spmm_gather<<<(NNODES * 64) / 256, 256, 0, stream>>>(
                cnt, pairs,
                out + (size_t)(l - 1) * DIM,
                out + (size_t)l * DIM);
        }
    } else {
        init_out_full<<<(NNODES * 64 + 255) / 256, 256, 0, stream>>>(user_emb, item_emb, out);
        for (int l = 1; l <= 3; ++l) {
            scatter_spmm<<<(NNZ * 16) / 256, 256, 0, stream>>>(
                esrc, edst, eval,
                out + (size_t)(l - 1) * DIM,
                out + (size_t)l * DIM);
        }
    }
}

// Round 10
// 1078.063 us; speedup vs baseline: 1.8459x; 1.0141x over previous
//
#include <hip/hip_runtime.h>
#include <hip/hip_fp16.h>
#include <stdint.h>

#define U_NUM   100000
#define NNODES  200000
#define DIM     64
#define OUTDIM  256
#define NNZ     6400000

// ---- bucket decomposition ----
#define BSHIFT  6
#define BNODES  64                      // nodes per bucket (200000/64 = 3125 exact)
#define NB      (NNODES >> BSHIFT)      // 3125 buckets
#define BCAP    4096                    // LDS capacity per bucket (mean 2048, sd ~45)
#define NBLK    256                     // partition blocks
#define EPB     (NNZ / NBLK)            // 25000 edges per partition block

// ---------- ws layout ----------
// [0, 800000)                  : uint32 rowend (NNODES)
// [800000, 800000+NNZ*8)       : int2 pairs {packed_src_dlow | src, f32bits(val)}
// [52000000, +NB*4)            : uint32 bcnt (bucket counts -> exclusive starts)
// [52012500, +NBLK*NB*4)       : uint32 partials (per-block per-bucket offsets)
// [55220000, +25.6MB)          : fp16 mirror A (gather source)
// [80820000, +25.6MB)          : fp16 mirror B
#define WS_ROWEND    0
#define WS_PAIRS     800000
#define WS_BCNT      52000000
#define WS_PART      52012500
#define WS_NEEDED_NEW ((size_t)WS_PART + (size_t)NBLK * NB * 4)   // 55,212,500
#define WS_MIR0      55220000
#define WS_MIR1      (WS_MIR0 + (size_t)NNODES * DIM * 2)         // 80,820,000
#define WS_NEEDED_H  (WS_MIR1 + (size_t)NNODES * DIM * 2)         // 106,420,000
#define WS_NEEDED_OLD (800000 + (size_t)NNZ * 8)                  // 52,000,000

// Copy ego (user||item) into cols 0..63 of out (fp32). Layers 1..3 write 64..255.
__global__ void init_out(const float* __restrict__ user_emb,
                         const float* __restrict__ item_emb,
                         float* __restrict__ out) {
    int t = blockIdx.x * blockDim.x + threadIdx.x;   // NNODES*16 threads
    if (t >= NNODES * 16) return;
    int n = t >> 4;
    int c = (t & 15) << 2;
    const float* s = (n < U_NUM) ? (user_emb + (size_t)n * DIM + c)
                                 : (item_emb + (size_t)(n - U_NUM) * DIM + c);
    *(float4*)(out + (size_t)n * OUTDIM + c) = *(const float4*)s;
}

// Same, but also write an fp16 mirror of the ego slice (gather source for layer 1).
__global__ void init_out_h(const float* __restrict__ user_emb,
                           const float* __restrict__ item_emb,
                           float* __restrict__ out,
                           __half* __restrict__ mir) {
    int t = blockIdx.x * blockDim.x + threadIdx.x;   // NNODES*16 threads
    if (t >= NNODES * 16) return;
    int n = t >> 4;
    int c = (t & 15) << 2;
    const float* s = (n < U_NUM) ? (user_emb + (size_t)n * DIM + c)
                                 : (item_emb + (size_t)(n - U_NUM) * DIM + c);
    float4 v = *(const float4*)s;
    *(float4*)(out + (size_t)n * OUTDIM + c) = v;
    __half2 h01 = __floats2half2_rn(v.x, v.y);
    __half2 h23 = __floats2half2_rn(v.z, v.w);
    uint2 u;
    u.x = *(uint32_t*)&h01;
    u.y = *(uint32_t*)&h23;
    *(uint2*)(mir + (size_t)n * DIM + c) = u;
}

// ===================== radix partition (unchanged, proven) =====================

__global__ __launch_bounds__(1024) void bucket_hist(const int* __restrict__ edst,
                                                    uint32_t* __restrict__ partials) {
    __shared__ uint32_t h[NB];
    for (int i = threadIdx.x; i < NB; i += 1024) h[i] = 0u;
    __syncthreads();
    int blk = blockIdx.x;
    int e0 = blk * EPB;
    for (int i = threadIdx.x; i < EPB; i += 1024)
        atomicAdd(&h[(uint32_t)edst[e0 + i] >> BSHIFT], 1u);
    __syncthreads();
    for (int i = threadIdx.x; i < NB; i += 1024)
        partials[(size_t)blk * NB + i] = h[i];
}

__global__ void bucket_colsum(const uint32_t* __restrict__ partials,
                              uint32_t* __restrict__ bcnt) {
    int b = blockIdx.x * blockDim.x + threadIdx.x;
    if (b >= NB) return;
    uint32_t s = 0u;
    for (int blk = 0; blk < NBLK; ++blk) s += partials[(size_t)blk * NB + b];
    bcnt[b] = s;
}

__global__ __launch_bounds__(1024) void scan_bcnt(uint32_t* __restrict__ cnt) {
    __shared__ uint32_t lds[1024];
    __shared__ uint32_t s_carry;
    int t = threadIdx.x;
    if (t == 0) s_carry = 0u;
    __syncthreads();
    for (int base = 0; base < NB; base += 1024) {
        int i = base + t;
        uint32_t v = (i < NB) ? cnt[i] : 0u;
        lds[t] = v;
        __syncthreads();
        for (int off = 1; off < 1024; off <<= 1) {
            uint32_t add = (t >= off) ? lds[t - off] : 0u;
            __syncthreads();
            lds[t] += add;
            __syncthreads();
        }
        uint32_t incl  = lds[t];
        uint32_t total = lds[1023];
        uint32_t c     = s_carry;
        __syncthreads();
        if (i < NB) cnt[i] = incl - v + c;           // exclusive + carry
        if (t == 0) s_carry = c + total;
        __syncthreads();
    }
}

__global__ void bucket_offsets(uint32_t* __restrict__ partials,
                               const uint32_t* __restrict__ bstart) {
    int b = blockIdx.x * blockDim.x + threadIdx.x;
    if (b >= NB) return;
    uint32_t run = bstart[b];
    for (int blk = 0; blk < NBLK; ++blk) {
        size_t idx = (size_t)blk * NB + b;
        uint32_t t = partials[idx];
        partials[idx] = run;
        run += t;
    }
}

__global__ __launch_bounds__(1024) void scatter_buckets(const int*   __restrict__ esrc,
                                                        const int*   __restrict__ edst,
                                                        const float* __restrict__ eval,
                                                        const uint32_t* __restrict__ partials,
                                                        int2* __restrict__ pairs) {
    __shared__ uint32_t cur[NB];
    int blk = blockIdx.x;
    for (int i = threadIdx.x; i < NB; i += 1024)
        cur[i] = partials[(size_t)blk * NB + i];
    __syncthreads();
    int e0 = blk * EPB;
    for (int i = threadIdx.x; i < EPB; i += 1024) {
        int e = e0 + i;
        int d = edst[e];
        int b = (uint32_t)d >> BSHIFT;
        uint32_t pos = atomicAdd(&cur[b], 1u);
        int packed = esrc[e] | ((d & (BNODES - 1)) << 18);   // src<2^18, dlow in [18,24)
        pairs[pos] = make_int2(packed, __float_as_int(eval[e]));
    }
}

__global__ __launch_bounds__(256) void bucket_sort(const uint32_t* __restrict__ bstart_arr,
                                                   int2* __restrict__ pairs,
                                                   uint32_t* __restrict__ rowend) {
    __shared__ int2 ebuf[BCAP];
    __shared__ uint32_t scnt[BNODES];
    int b = blockIdx.x;
    uint32_t start = bstart_arr[b];
    uint32_t end   = (b == NB - 1) ? (uint32_t)NNZ : bstart_arr[b + 1];
    int n = (int)(end - start);
    if (n > BCAP) n = BCAP;                          // safety clamp
    if (threadIdx.x < BNODES) scnt[threadIdx.x] = 0u;
    __syncthreads();
    for (int i = threadIdx.x; i < n; i += 256) {
        int2 e = pairs[start + i];
        ebuf[i] = e;
        atomicAdd(&scnt[(uint32_t)e.x >> 18], 1u);
    }
    __syncthreads();
    if (threadIdx.x < 64) {                          // wave 0: inclusive scan of 64 counters
        uint32_t c = scnt[threadIdx.x];
        uint32_t v = c;
        for (int off = 1; off < 64; off <<= 1) {
            uint32_t nv = __shfl_up(v, (unsigned)off, 64);
            if ((int)threadIdx.x >= off) v += nv;
        }
        rowend[b * BNODES + threadIdx.x] = start + v;   // global end offset per node
        scnt[threadIdx.x] = v - c;                      // exclusive -> write cursor
    }
    __syncthreads();
    for (int i = threadIdx.x; i < n; i += 256) {
        int2 e = ebuf[i];
        int dlow = (uint32_t)e.x >> 18;
        uint32_t pos = start + atomicAdd(&scnt[dlow], 1u);
        pairs[pos] = make_int2(e.x & 0x3FFFF, e.y);     // strip dlow bits
    }
}

// ===================== gather SpMM =====================

// 4-deep masked unroll of the 8-edge gather: 32 edges in flight per iteration.
// Lane layout: g = lane>>3 (edge slot), l = lane&7 (column octet). Four
// independent {pairs-load -> 16B gather} chains issue back-to-back, so each
// wave keeps ~4 gathers outstanding (vs 2 in the h8 version). Masked slots
// gather dummy row 0 with v=0 (one hot line, no extra fetch).
__global__ __launch_bounds__(256) void spmm_gather_h32(const uint32_t* __restrict__ rowend,
                                                       const int2*     __restrict__ pairs,
                                                       const __half*   __restrict__ mirp,
                                                       float*          __restrict__ cur,
                                                       __half*         __restrict__ mirc) {
    int w    = (blockIdx.x * blockDim.x + threadIdx.x) >> 6;  // row id
    int lane = threadIdx.x & 63;
    if (w >= NNODES) return;
    uint32_t start = (w == 0) ? 0u : rowend[w - 1];
    uint32_t end   = rowend[w];
    int g = lane >> 3;                    // edge slot 0..7
    int l = lane & 7;                     // column octet 0..7

    float acc0 = 0.f, acc1 = 0.f, acc2 = 0.f, acc3 = 0.f;
    float acc4 = 0.f, acc5 = 0.f, acc6 = 0.f, acc7 = 0.f;

    for (uint32_t i = start; i < end; i += 32) {
        uint32_t i0 = i + (uint32_t)g;
        uint32_t i1 = i0 + 8;
        uint32_t i2 = i0 + 16;
        uint32_t i3 = i0 + 24;
        int2 p0 = (i0 < end) ? pairs[i0] : make_int2(0, 0);
        int2 p1 = (i1 < end) ? pairs[i1] : make_int2(0, 0);
        int2 p2 = (i2 < end) ? pairs[i2] : make_int2(0, 0);
        int2 p3 = (i3 < end) ? pairs[i3] : make_int2(0, 0);
        uint4 hv0 = *((const uint4*)(mirp + (size_t)p0.x * DIM) + l);
        uint4 hv1 = *((const uint4*)(mirp + (size_t)p1.x * DIM) + l);
        uint4 hv2 = *((const uint4*)(mirp + (size_t)p2.x * DIM) + l);
        uint4 hv3 = *((const uint4*)(mirp + (size_t)p3.x * DIM) + l);
        float v0 = __int_as_float(p0.y);
        float v1 = __int_as_float(p1.y);
        float v2 = __int_as_float(p2.y);
        float v3 = __int_as_float(p3.y);
        {
            float2 f0 = __half22float2(*(__half2*)&hv0.x);
            float2 f1 = __half22float2(*(__half2*)&hv0.y);
            float2 f2 = __half22float2(*(__half2*)&hv0.z);
            float2 f3 = __half22float2(*(__half2*)&hv0.w);
            acc0 = fmaf(f0.x, v0, acc0); acc1 = fmaf(f0.y, v0, acc1);
            acc2 = fmaf(f1.x, v0, acc2); acc3 = fmaf(f1.y, v0, acc3);
            acc4 = fmaf(f2.x, v0, acc4); acc5 = fmaf(f2.y, v0, acc5);
            acc6 = fmaf(f3.x, v0, acc6); acc7 = fmaf(f3.y, v0, acc7);
        }
        {
            float2 f0 = __half22float2(*(__half2*)&hv1.x);
            float2 f1 = __half22float2(*(__half2*)&hv1.y);
            float2 f2 = __half22float2(*(__half2*)&hv1.z);
            float2 f3 = __half22float2(*(__half2*)&hv1.w);
            acc0 = fmaf(f0.x, v1, acc0); acc1 = fmaf(f0.y, v1, acc1);
            acc2 = fmaf(f1.x, v1, acc2); acc3 = fmaf(f1.y, v1, acc3);
            acc4 = fmaf(f2.x, v1, acc4); acc5 = fmaf(f2.y, v1, acc5);
            acc6 = fmaf(f3.x, v1, acc6); acc7 = fmaf(f3.y, v1, acc7);
        }
        {
            float2 f0 = __half22float2(*(__half2*)&hv2.x);
            float2 f1 = __half22float2(*(__half2*)&hv2.y);
            float2 f2 = __half22float2(*(__half2*)&hv2.z);
            float2 f3 = __half22float2(*(__half2*)&hv2.w);
            acc0 = fmaf(f0.x, v2, acc0); acc1 = fmaf(f0.y, v2, acc1);
            acc2 = fmaf(f1.x, v2, acc2); acc3 = fmaf(f1.y, v2, acc3);
            acc4 = fmaf(f2.x, v2, acc4); acc5 = fmaf(f2.y, v2, acc5);
            acc6 = fmaf(f3.x, v2, acc6); acc7 = fmaf(f3.y, v2, acc7);
        }
        {
            float2 f0 = __half22float2(*(__half2*)&hv3.x);
            float2 f1 = __half22float2(*(__half2*)&hv3.y);
            float2 f2 = __half22float2(*(__half2*)&hv3.z);
            float2 f3 = __half22float2(*(__half2*)&hv3.w);
            acc0 = fmaf(f0.x, v3, acc0); acc1 = fmaf(f0.y, v3, acc1);
            acc2 = fmaf(f1.x, v3, acc2); acc3 = fmaf(f1.y, v3, acc3);
            acc4 = fmaf(f2.x, v3, acc4); acc5 = fmaf(f2.y, v3, acc5);
            acc6 = fmaf(f3.x, v3, acc6); acc7 = fmaf(f3.y, v3, acc7);
        }
    }

    // combine the 8 edge slots (lane bits 3..5)
    #pragma unroll
    for (int off = 8; off < 64; off <<= 1) {
        acc0 += __shfl_xor(acc0, off, 64);
        acc1 += __shfl_xor(acc1, off, 64);
        acc2 += __shfl_xor(acc2, off, 64);
        acc3 += __shfl_xor(acc3, off, 64);
        acc4 += __shfl_xor(acc4, off, 64);
        acc5 += __shfl_xor(acc5, off, 64);
        acc6 += __shfl_xor(acc6, off, 64);
        acc7 += __shfl_xor(acc7, off, 64);
    }

    if (lane < 8) {                       // g==0 lanes hold cols 8l..8l+7
        float* op = cur + (size_t)w * OUTDIM + 8 * l;
        *(float4*)(op + 0) = make_float4(acc0, acc1, acc2, acc3);
        *(float4*)(op + 4) = make_float4(acc4, acc5, acc6, acc7);
        if (mirc) {
            __half2 a0 = __floats2half2_rn(acc0, acc1);
            __half2 a1 = __floats2half2_rn(acc2, acc3);
            __half2 a2 = __floats2half2_rn(acc4, acc5);
            __half2 a3 = __floats2half2_rn(acc6, acc7);
            uint4 u;
            u.x = *(uint32_t*)&a0;
            u.y = *(uint32_t*)&a1;
            u.z = *(uint32_t*)&a2;
            u.w = *(uint32_t*)&a3;
            *(uint4*)(mirc + (size_t)w * DIM + 8 * l) = u;
        }
    }
}

// fp32-source variant (proven R1 path, mid-tier fallback).
__global__ __launch_bounds__(256) void spmm_gather(const uint32_t* __restrict__ rowend,
                                                   const int2*     __restrict__ pairs,
                                                   const float*    __restrict__ prev,
                                                   float*          __restrict__ cur) {
    int w    = (blockIdx.x * blockDim.x + threadIdx.x) >> 6;  // row id
    int lane = threadIdx.x & 63;
    if (w >= NNODES) return;
    uint32_t start = (w == 0) ? 0u : rowend[w - 1];
    uint32_t end   = rowend[w];
    float acc = 0.f;
    uint32_t i = start;
    for (; i + 4 <= end; i += 4) {
        int2 p0 = pairs[i + 0];
        int2 p1 = pairs[i + 1];
        int2 p2 = pairs[i + 2];
        int2 p3 = pairs[i + 3];
        float x0 = prev[(size_t)p0.x * OUTDIM + lane];
        float x1 = prev[(size_t)p1.x * OUTDIM + lane];
        float x2 = prev[(size_t)p2.x * OUTDIM + lane];
        float x3 = prev[(size_t)p3.x * OUTDIM + lane];
        acc = fmaf(x0, __int_as_float(p0.y), acc);
        acc = fmaf(x1, __int_as_float(p1.y), acc);
        acc = fmaf(x2, __int_as_float(p2.y), acc);
        acc = fmaf(x3, __int_as_float(p3.y), acc);
    }
    for (; i < end; ++i) {
        int2 p = pairs[i];
        acc = fmaf(prev[(size_t)p.x * OUTDIM + lane], __int_as_float(p.y), acc);
    }
    cur[(size_t)w * OUTDIM + lane] = acc;
}

// ===================== OLD PATH helpers (proven) =====================

__global__ void zero_cnt(uint32_t* __restrict__ cnt) {
    int t = blockIdx.x * blockDim.x + threadIdx.x;
    if (t < NNODES) cnt[t] = 0u;
}

__global__ void hist(const int* __restrict__ edst, uint32_t* __restrict__ cnt) {
    int e = blockIdx.x * blockDim.x + threadIdx.x;
    if (e < NNZ) atomicAdd(&cnt[edst[e]], 1u);
}

__global__ __launch_bounds__(1024) void scan_cnt(uint32_t* __restrict__ cnt) {
    __shared__ uint32_t lds[1024];
    __shared__ uint32_t s_carry;
    int t = threadIdx.x;
    if (t == 0) s_carry = 0u;
    __syncthreads();
    for (int base = 0; base < NNODES; base += 1024) {
        int i = base + t;
        uint32_t v = (i < NNODES) ? cnt[i] : 0u;
        lds[t] = v;
        __syncthreads();
        for (int off = 1; off < 1024; off <<= 1) {
            uint32_t add = (t >= off) ? lds[t - off] : 0u;
            __syncthreads();
            lds[t] += add;
            __syncthreads();
        }
        uint32_t incl  = lds[t];
        uint32_t total = lds[1023];
        uint32_t c     = s_carry;
        __syncthreads();
        if (i < NNODES) cnt[i] = incl - v + c;
        if (t == 0) s_carry = c + total;
        __syncthreads();
    }
}

__global__ void fill_pairs(const int*   __restrict__ esrc,
                           const int*   __restrict__ edst,
                           const float* __restrict__ eval,
                           uint32_t*    __restrict__ cnt,
                           int2*        __restrict__ pairs) {
    int e = blockIdx.x * blockDim.x + threadIdx.x;
    if (e >= NNZ) return;
    int d = edst[e];
    uint32_t pos = atomicAdd(&cnt[d], 1u);
    pairs[pos] = make_int2(esrc[e], __float_as_int(eval[e]));
}

// ---------- fallback (atomics) if ws too small ----------
__global__ void init_out_full(const float* __restrict__ user_emb,
                              const float* __restrict__ item_emb,
                              float* __restrict__ out) {
    int t = blockIdx.x * blockDim.x + threadIdx.x;
    if (t >= NNODES * 64) return;
    int n = t >> 6;
    int c = (t & 63) << 2;
    float4 v = make_float4(0.f, 0.f, 0.f, 0.f);
    if (c < DIM) {
        const float* s = (n < U_NUM) ? (user_emb + (size_t)n * DIM + c)
                                     : (item_emb + (size_t)(n - U_NUM) * DIM + c);
        v = *(const float4*)s;
    }
    *(float4*)(out + (size_t)n * OUTDIM + c) = v;
}

__global__ void scatter_spmm(const int*   __restrict__ esrc,
                             const int*   __restrict__ edst,
                             const float* __restrict__ eval,
                             const float* __restrict__ prev,
                             float*       __restrict__ cur) {
    int t = blockIdx.x * blockDim.x + threadIdx.x;
    if (t >= NNZ * 16) return;
    int e = t >> 4;
    int j = (t & 15) << 2;
    int s = esrc[e];
    int d = edst[e];
    float v = eval[e];
    float4 x = *(const float4*)(prev + (size_t)s * OUTDIM + j);
    float* ap = cur + (size_t)d * OUTDIM + j;
    unsafeAtomicAdd(ap + 0, x.x * v);
    unsafeAtomicAdd(ap + 1, x.y * v);
    unsafeAtomicAdd(ap + 2, x.z * v);
    unsafeAtomicAdd(ap + 3, x.w * v);
}

extern "C" void kernel_launch(void* const* d_in, const int* in_sizes, int n_in,
                              void* d_out, int out_size, void* d_ws, size_t ws_size,
                              hipStream_t stream) {
    const float* user_emb = (const float*)d_in[0];
    const float* item_emb = (const float*)d_in[1];
    const float* eval     = (const float*)d_in[2];
    const int*   esrc     = (const int*)d_in[3];
    const int*   edst     = (const int*)d_in[4];
    float* out = (float*)d_out;                      // 200000 x 256 f32

    if (ws_size >= WS_NEEDED_H) {
        // ---- fp16-mirror path, 32-edge deep-pipelined gather ----
        uint32_t* rowend   = (uint32_t*)((char*)d_ws + WS_ROWEND);
        int2*     pairs    = (int2*)   ((char*)d_ws + WS_PAIRS);
        uint32_t* bcnt     = (uint32_t*)((char*)d_ws + WS_BCNT);
        uint32_t* partials = (uint32_t*)((char*)d_ws + WS_PART);
        __half*   mir0     = (__half*) ((char*)d_ws + WS_MIR0);
        __half*   mir1     = (__half*) ((char*)d_ws + WS_MIR1);

        init_out_h<<<(NNODES * 16 + 255) / 256, 256, 0, stream>>>(user_emb, item_emb, out, mir0);
        bucket_hist<<<NBLK, 1024, 0, stream>>>(edst, partials);
        bucket_colsum<<<(NB + 255) / 256, 256, 0, stream>>>(partials, bcnt);
        scan_bcnt<<<1, 1024, 0, stream>>>(bcnt);
        bucket_offsets<<<(NB + 255) / 256, 256, 0, stream>>>(partials, bcnt);
        scatter_buckets<<<NBLK, 1024, 0, stream>>>(esrc, edst, eval, partials, pairs);
        bucket_sort<<<NB, 256, 0, stream>>>(bcnt, pairs, rowend);

        // layer1: mir0 -> out[64..127] + mir1
        spmm_gather_h32<<<(NNODES * 64) / 256, 256, 0, stream>>>(
            rowend, pairs, mir0, out + (size_t)1 * DIM, mir1);
        // layer2: mir1 -> out[128..191] + mir0
        spmm_gather_h32<<<(NNODES * 64) / 256, 256, 0, stream>>>(
            rowend, pairs, mir1, out + (size_t)2 * DIM, mir0);
        // layer3: mir0 -> out[192..255], no mirror write
        spmm_gather_h32<<<(NNODES * 64) / 256, 256, 0, stream>>>(
            rowend, pairs, mir0, out + (size_t)3 * DIM, (__half*)nullptr);
    } else if (ws_size >= WS_NEEDED_NEW) {
        // ---- R1 proven fp32 path ----
        uint32_t* rowend   = (uint32_t*)((char*)d_ws + WS_ROWEND);
        int2*     pairs    = (int2*)   ((char*)d_ws + WS_PAIRS);
        uint32_t* bcnt     = (uint32_t*)((char*)d_ws + WS_BCNT);
        uint32_t* partials = (uint32_t*)((char*)d_ws + WS_PART);

        init_out<<<(NNODES * 16 + 255) / 256, 256, 0, stream>>>(user_emb, item_emb, out);
        bucket_hist<<<NBLK, 1024, 0, stream>>>(edst, partials);
        bucket_colsum<<<(NB + 255) / 256, 256, 0, stream>>>(partials, bcnt);
        scan_bcnt<<<1, 1024, 0, stream>>>(bcnt);
        bucket_offsets<<<(NB + 255) / 256, 256, 0, stream>>>(partials, bcnt);
        scatter_buckets<<<NBLK, 1024, 0, stream>>>(esrc, edst, eval, partials, pairs);
        bucket_sort<<<NB, 256, 0, stream>>>(bcnt, pairs, rowend);

        for (int l = 1; l <= 3; ++l) {
            spmm_gather<<<(NNODES * 64) / 256, 256, 0, stream>>>(
                rowend, pairs,
                out + (size_t)(l - 1) * DIM,
                out + (size_t)l * DIM);
        }
    } else if (ws_size >= WS_NEEDED_OLD) {
        uint32_t* cnt   = (uint32_t*)d_ws;
        int2*     pairs = (int2*)((char*)d_ws + 800000);

        init_out<<<(NNODES * 16 + 255) / 256, 256, 0, stream>>>(user_emb, item_emb, out);
        zero_cnt<<<(NNODES + 255) / 256, 256, 0, stream>>>(cnt);
        hist<<<NNZ / 256, 256, 0, stream>>>(edst, cnt);
        scan_cnt<<<1, 1024, 0, stream>>>(cnt);
        fill_pairs<<<NNZ / 256, 256, 0, stream>>>(esrc, edst, eval, cnt, pairs);

        for (int l = 1; l <= 3; ++l) {
            spmm_gather<<<(NNODES * 64) / 256, 256, 0, stream>>>(
                cnt, pairs,
                out + (size_t)(l - 1) * DIM,
                out + (size_t)l * DIM);
        }
    } else {
        init_out_full<<<(NNODES * 64 + 255) / 256, 256, 0, stream>>>(user_emb, item_emb, out);
        for (int l = 1; l <= 3; ++l) {
            scatter_spmm<<<(NNZ * 16) / 256, 256, 0, stream>>>(
                esrc, edst, eval,
                out + (size_t)(l - 1) * DIM,
                out + (size_t)l * DIM);
        }
    }
}